// Round 1
// baseline (1350.656 us; speedup 1.0000x reference)
//
#include <hip/hip_runtime.h>

// Decode attention with projections algebraically folded:
//   score[b,h,n] = (x[b,n,:]·qk[b,h,:] + qb[b,h]) * 1/sqrt(dh)
//   ctx[b,h,:]   = softmax-weighted sum of x rows  (only thing needing the big pass)
//   out = q + (ctx @ Wv[:,h] + bv) @ Wo + bo
// Big pass reads x exactly once (268 MB) -> memory-bound target ~43us floor.

namespace {
constexpr int DIMC = 256;
constexpr int NHEAD = 8;
constexpr int NTOKENS = 8192;
constexpr int NBATCH = 32;
constexpr int TOK_PER_BLOCK = 128;
constexpr int CHUNKS = NTOKENS / TOK_PER_BLOCK;  // 64
constexpr float SCALE = 0.17677669529663687f;    // 1/sqrt(32)

// workspace layout (float offsets); total 131584 floats = 526336 bytes
constexpr int WS_SCTX = 0;                             // [32][8][256] sum of e*x
constexpr int WS_L    = NBATCH * NHEAD * DIMC;         // [32][8]      sum of e
constexpr int WS_QK   = WS_L + NBATCH * NHEAD;         // [32][8][256]
constexpr int WS_QB   = WS_QK + NBATCH * NHEAD * DIMC; // [32][8]
}  // namespace

template <int CTRL>
__device__ __forceinline__ float dppmov(float v) {
  return __int_as_float(
      __builtin_amdgcn_update_dpp(0, __float_as_int(v), CTRL, 0xF, 0xF, true));
}
template <int PAT>
__device__ __forceinline__ float swzf(float v) {
  return __int_as_float(__builtin_amdgcn_ds_swizzle(__float_as_int(v), PAT));
}

// ---------------- K1: Q = x[b,0,:]@Wq+bq ; qk[b,h,:] = Wk[:,hcols]@Q ; zero accums
__global__ __launch_bounds__(256) void k1_prep(
    const float* __restrict__ x, const float* __restrict__ Wq,
    const float* __restrict__ bq, const float* __restrict__ Wk,
    const float* __restrict__ bk, float* __restrict__ qk_g,
    float* __restrict__ qb_g, float* __restrict__ sctx_g,
    float* __restrict__ l_g) {
  const int b = blockIdx.x, tid = threadIdx.x;
  __shared__ float xs[DIMC];
  __shared__ float Qs[DIMC];
  xs[tid] = x[(size_t)b * NTOKENS * DIMC + tid];
  // zero the atomic accumulators for this batch (ws is poisoned each launch)
#pragma unroll
  for (int r = 0; r < NHEAD; ++r) sctx_g[b * NHEAD * DIMC + r * DIMC + tid] = 0.f;
  if (tid < NHEAD) l_g[b * NHEAD + tid] = 0.f;
  __syncthreads();
  float acc = bq[tid];
#pragma unroll 4
  for (int d = 0; d < DIMC; ++d) acc += xs[d] * Wq[d * DIMC + tid];  // coalesced in tid
  Qs[tid] = acc;
  __syncthreads();
#pragma unroll
  for (int h = 0; h < NHEAD; ++h) {
    float s = 0.f;
#pragma unroll
    for (int j = 0; j < 32; ++j) s += Qs[h * 32 + j] * Wk[tid * DIMC + h * 32 + j];
    qk_g[b * NHEAD * DIMC + h * DIMC + tid] = s;
  }
  if (tid < NHEAD) {
    float s = 0.f;
#pragma unroll
    for (int j = 0; j < 32; ++j) s += Qs[tid * 32 + j] * bk[tid * 32 + j];
    qb_g[b * NHEAD + tid] = s;
  }
}

// ---------------- K2: streaming pass over x. One float4/lane per token.
// Lane i owns d = 4i..4i+3. Head partials reduced with DPP (xor1/2/8),
// ds_swizzle (xor4/16), shfl (xor32); quad-select so only 2 values ride the
// long reduction. sctx slots use XOR head labeling: slot j<4 -> head (lane&3)^j,
// slot 4+j -> head 4+((lane&3)^j); resolved once at the atomic write-out.
__global__ __launch_bounds__(256) void k2_attn(
    const float* __restrict__ x, const float* __restrict__ qk_g,
    const float* __restrict__ qb_g, float* __restrict__ sctx_g,
    float* __restrict__ l_g) {
  const int b = blockIdx.x >> 6;
  const int chunk = blockIdx.x & (CHUNKS - 1);
  const int tid = threadIdx.x;
  const int wave = tid >> 6;
  const int lane = tid & 63;
  const int q2 = lane & 3;

  // qk fragments in natural head order: qk[h] covers d = 4*lane .. 4*lane+3
  const float4* qkp = (const float4*)(qk_g + b * NHEAD * DIMC);
  float4 qk[8];
#pragma unroll
  for (int h = 0; h < 8; ++h) qk[h] = qkp[h * 64 + lane];
  const float qba = qb_g[b * 8 + q2];
  const float qbb = qb_g[b * 8 + 4 + q2];

  float4 sc[8];
#pragma unroll
  for (int j = 0; j < 8; ++j) sc[j] = make_float4(0.f, 0.f, 0.f, 0.f);
  float laccA = 0.f, laccB = 0.f;

  const int n0 = chunk * TOK_PER_BLOCK + wave * 32;
  const float4* xp = (const float4*)(x + (size_t)b * NTOKENS * DIMC);
  float4 xv = xp[(size_t)n0 * 64 + lane];
  for (int t = 0; t < 32; ++t) {
    const int tn = (t + 1) & 31;  // wrap reload at t=31 (L1 hit, branchless)
    float4 xn = xp[(size_t)(n0 + tn) * 64 + lane];

    // per-lane head partials over 4 d's
    float p[8];
#pragma unroll
    for (int h = 0; h < 8; ++h)
      p[h] = xv.x * qk[h].x + xv.y * qk[h].y + xv.z * qk[h].z + xv.w * qk[h].w;
    // quad reduce (xor1, xor2) on all 8 — DPP, VALU pipe
#pragma unroll
    for (int h = 0; h < 8; ++h) {
      p[h] += dppmov<0xB1>(p[h]);  // quad_perm [1,0,3,2] = xor1
      p[h] += dppmov<0x4E>(p[h]);  // quad_perm [2,3,0,1] = xor2
    }
    // each lane carries 2 of the 8 quad-sums onward
    const bool c0 = (lane & 1) != 0, c1 = (lane & 2) != 0;
    float t0 = c0 ? p[1] : p[0], t1 = c0 ? p[3] : p[2];
    float s0 = c0 ? p[5] : p[4], s1 = c0 ? p[7] : p[6];
    float va = c1 ? t1 : t0;   // -> head q2
    float vb = c1 ? s1 : s0;   // -> head 4+q2
    va += swzf<0x101F>(va); vb += swzf<0x101F>(vb);    // xor4  (ds_swizzle)
    va += dppmov<0x128>(va); vb += dppmov<0x128>(vb);  // xor8  (row_ror:8)
    va += swzf<0x401F>(va); vb += swzf<0x401F>(vb);    // xor16 (ds_swizzle)
    va += __shfl_xor(va, 32, 64); vb += __shfl_xor(vb, 32, 64);  // xor32

    const float ea = __expf((va + qba) * SCALE);
    const float eb = __expf((vb + qbb) * SCALE);
    laccA += ea; laccB += eb;

    // spread e to all lanes in XOR slot order (3 DPP movs per value)
    float r[8];
    r[0] = ea; r[1] = dppmov<0xB1>(ea);
    r[2] = dppmov<0x4E>(ea); r[3] = dppmov<0x4E>(r[1]);
    r[4] = eb; r[5] = dppmov<0xB1>(eb);
    r[6] = dppmov<0x4E>(eb); r[7] = dppmov<0x4E>(r[5]);
#pragma unroll
    for (int j = 0; j < 8; ++j) {
      sc[j].x += r[j] * xv.x; sc[j].y += r[j] * xv.y;
      sc[j].z += r[j] * xv.z; sc[j].w += r[j] * xv.w;
    }
    xv = xn;
  }

  float* sb = sctx_g + b * NHEAD * DIMC;
  const int dbase = lane * 4;
#pragma unroll
  for (int j = 0; j < 8; ++j) {
    const int h = (j < 4) ? (q2 ^ j) : (4 + (q2 ^ (j - 4)));
    atomicAdd(&sb[h * DIMC + dbase + 0], sc[j].x);
    atomicAdd(&sb[h * DIMC + dbase + 1], sc[j].y);
    atomicAdd(&sb[h * DIMC + dbase + 2], sc[j].z);
    atomicAdd(&sb[h * DIMC + dbase + 3], sc[j].w);
  }
  if (lane < 4) {
    atomicAdd(&l_g[b * 8 + lane], laccA);
    atomicAdd(&l_g[b * 8 + 4 + lane], laccB);
  }
}

// ---------------- K3: o = ctx/l @ Wv[:,hcols] + bv ; out = q + o @ Wo + bo
__global__ __launch_bounds__(256) void k3_final(
    const float* __restrict__ x, const float* __restrict__ Wv,
    const float* __restrict__ bv, const float* __restrict__ Wo,
    const float* __restrict__ bo, const float* __restrict__ sctx_g,
    const float* __restrict__ l_g, float* __restrict__ out) {
  const int b = blockIdx.x, tid = threadIdx.x;
  __shared__ float ctxs[NHEAD * DIMC];
  __shared__ float os[DIMC];
  __shared__ float ls[NHEAD];
#pragma unroll
  for (int r = 0; r < NHEAD; ++r)
    ctxs[r * DIMC + tid] = sctx_g[b * NHEAD * DIMC + r * DIMC + tid];
  if (tid < NHEAD) ls[tid] = l_g[b * NHEAD + tid];
  __syncthreads();
  const int h = tid >> 5;
  float s = 0.f;
#pragma unroll 4
  for (int d = 0; d < DIMC; ++d) s += ctxs[h * DIMC + d] * Wv[d * DIMC + tid];
  const float o = s / ls[h] + bv[tid];
  os[tid] = o;
  __syncthreads();
  float acc = bo[tid] + x[(size_t)b * NTOKENS * DIMC + tid];  // q residual
#pragma unroll 4
  for (int j = 0; j < DIMC; ++j) acc += os[j] * Wo[j * DIMC + tid];
  out[b * DIMC + tid] = acc;
}

extern "C" void kernel_launch(void* const* d_in, const int* in_sizes, int n_in,
                              void* d_out, int out_size, void* d_ws, size_t ws_size,
                              hipStream_t stream) {
  const float* x  = (const float*)d_in[0];
  const float* Wq = (const float*)d_in[1];
  const float* bq = (const float*)d_in[2];
  const float* Wk = (const float*)d_in[3];
  const float* bk = (const float*)d_in[4];
  const float* Wv = (const float*)d_in[5];
  const float* bv = (const float*)d_in[6];
  const float* Wo = (const float*)d_in[7];
  const float* bo = (const float*)d_in[8];
  float* ws = (float*)d_ws;
  float* sctx = ws + WS_SCTX;
  float* lg   = ws + WS_L;
  float* qk   = ws + WS_QK;
  float* qb   = ws + WS_QB;

  k1_prep<<<NBATCH, 256, 0, stream>>>(x, Wq, bq, Wk, bk, qk, qb, sctx, lg);
  k2_attn<<<NBATCH * CHUNKS, 256, 0, stream>>>(x, qk, qb, sctx, lg);
  k3_final<<<NBATCH, 256, 0, stream>>>(x, Wv, bv, Wo, bo, sctx, lg,
                                       (float*)d_out);
}

// Round 2
// 495.926 us; speedup vs baseline: 2.7235x; 2.7235x over previous
//
#include <hip/hip_runtime.h>

// Decode attention with projections algebraically folded:
//   score[b,h,n] = (x[b,n,:]·qk[b,h,:] + qb[b,h]) * 1/sqrt(dh)
//   ctx[b,h,:]   = softmax-weighted sum of x rows  (only thing needing the big pass)
//   out = q + (ctx @ Wv[:,h] + bv) @ Wo + bo
// Big pass reads x exactly once (268 MB) -> memory-bound target ~43us floor.
// R2: global atomics in k2 epilogue were memory-side RMW (537 MB of 32B txns,
// serialized on 32KB of contended lines) -> replaced with LDS wave-combine +
// plain per-chunk partial stores + k2b reduce kernel.

namespace {
constexpr int DIMC = 256;
constexpr int NHEAD = 8;
constexpr int NTOKENS = 8192;
constexpr int NBATCH = 32;
constexpr int TOK_PER_BLOCK = 128;
constexpr int CHUNKS = NTOKENS / TOK_PER_BLOCK;  // 64
constexpr float SCALE = 0.17677669529663687f;    // 1/sqrt(32)

// workspace layout (float offsets)
constexpr int WS_SCTX = 0;                              // [32][8][256] sum of e*x
constexpr int WS_L    = NBATCH * NHEAD * DIMC;          // [32][8]      sum of e
constexpr int WS_QK   = WS_L + NBATCH * NHEAD;          // [32][8][256]
constexpr int WS_QB   = WS_QK + NBATCH * NHEAD * DIMC;  // [32][8]
constexpr int WS_PART = WS_QB + NBATCH * NHEAD;         // [32][64][8][256] partials
constexpr size_t WS_NEEDED_BYTES =
    (size_t)(WS_PART + NBATCH * CHUNKS * NHEAD * DIMC) * 4;  // ~17.3 MB
}  // namespace

template <int CTRL>
__device__ __forceinline__ float dppmov(float v) {
  return __int_as_float(
      __builtin_amdgcn_update_dpp(0, __float_as_int(v), CTRL, 0xF, 0xF, true));
}
template <int PAT>
__device__ __forceinline__ float swzf(float v) {
  return __int_as_float(__builtin_amdgcn_ds_swizzle(__float_as_int(v), PAT));
}

// ---------------- K1: Q = x[b,0,:]@Wq+bq ; qk[b,h,:] = Wk[:,hcols]@Q ; zero accums
__global__ __launch_bounds__(256) void k1_prep(
    const float* __restrict__ x, const float* __restrict__ Wq,
    const float* __restrict__ bq, const float* __restrict__ Wk,
    const float* __restrict__ bk, float* __restrict__ qk_g,
    float* __restrict__ qb_g, float* __restrict__ sctx_g,
    float* __restrict__ l_g) {
  const int b = blockIdx.x, tid = threadIdx.x;
  __shared__ float xs[DIMC];
  __shared__ float Qs[DIMC];
  xs[tid] = x[(size_t)b * NTOKENS * DIMC + tid];
  // zero the accumulators for this batch (ws is poisoned each launch)
#pragma unroll
  for (int r = 0; r < NHEAD; ++r) sctx_g[b * NHEAD * DIMC + r * DIMC + tid] = 0.f;
  if (tid < NHEAD) l_g[b * NHEAD + tid] = 0.f;
  __syncthreads();
  float acc = bq[tid];
#pragma unroll 4
  for (int d = 0; d < DIMC; ++d) acc += xs[d] * Wq[d * DIMC + tid];  // coalesced in tid
  Qs[tid] = acc;
  __syncthreads();
#pragma unroll
  for (int h = 0; h < NHEAD; ++h) {
    float s = 0.f;
#pragma unroll
    for (int j = 0; j < 32; ++j) s += Qs[h * 32 + j] * Wk[tid * DIMC + h * 32 + j];
    qk_g[b * NHEAD * DIMC + h * DIMC + tid] = s;
  }
  if (tid < NHEAD) {
    float s = 0.f;
#pragma unroll
    for (int j = 0; j < 32; ++j) s += Qs[tid * 32 + j] * bk[tid * 32 + j];
    qb_g[b * NHEAD + tid] = s;
  }
}

// ---------------- K2: streaming pass over x. One float4/lane per token.
// Lane i owns d = 4i..4i+3. Head partials reduced with DPP (xor1/2/8),
// ds_swizzle (xor4/16), shfl (xor32); quad-select so only 2 values ride the
// long reduction. sctx slots use XOR head labeling: slot j<4 -> head (lane&3)^j,
// slot 4+j -> head 4+((lane&3)^j); resolved at the write-out (k2b for PARTIAL).
template <bool PARTIAL>
__global__ __launch_bounds__(256) void k2_attn(
    const float* __restrict__ x, const float* __restrict__ qk_g,
    const float* __restrict__ qb_g, float* __restrict__ dst_g,
    float* __restrict__ l_g) {
  const int b = blockIdx.x >> 6;
  const int chunk = blockIdx.x & (CHUNKS - 1);
  const int tid = threadIdx.x;
  const int wave = tid >> 6;
  const int lane = tid & 63;
  const int q2 = lane & 3;

  // qk fragments in natural head order: qk[h] covers d = 4*lane .. 4*lane+3
  const float4* qkp = (const float4*)(qk_g + b * NHEAD * DIMC);
  float4 qk[8];
#pragma unroll
  for (int h = 0; h < 8; ++h) qk[h] = qkp[h * 64 + lane];
  const float qba = qb_g[b * 8 + q2];
  const float qbb = qb_g[b * 8 + 4 + q2];

  float4 sc[8];
#pragma unroll
  for (int j = 0; j < 8; ++j) sc[j] = make_float4(0.f, 0.f, 0.f, 0.f);
  float laccA = 0.f, laccB = 0.f;

  const int n0 = chunk * TOK_PER_BLOCK + wave * 32;
  const float4* xp = (const float4*)(x + (size_t)b * NTOKENS * DIMC);
  float4 xv = xp[(size_t)n0 * 64 + lane];
  for (int t = 0; t < 32; ++t) {
    const int tn = (t + 1) & 31;  // wrap reload at t=31 (L1 hit, branchless)
    float4 xn = xp[(size_t)(n0 + tn) * 64 + lane];

    // per-lane head partials over 4 d's
    float p[8];
#pragma unroll
    for (int h = 0; h < 8; ++h)
      p[h] = xv.x * qk[h].x + xv.y * qk[h].y + xv.z * qk[h].z + xv.w * qk[h].w;
    // quad reduce (xor1, xor2) on all 8 — DPP, VALU pipe
#pragma unroll
    for (int h = 0; h < 8; ++h) {
      p[h] += dppmov<0xB1>(p[h]);  // quad_perm [1,0,3,2] = xor1
      p[h] += dppmov<0x4E>(p[h]);  // quad_perm [2,3,0,1] = xor2
    }
    // each lane carries 2 of the 8 quad-sums onward
    const bool c0 = (lane & 1) != 0, c1 = (lane & 2) != 0;
    float t0 = c0 ? p[1] : p[0], t1 = c0 ? p[3] : p[2];
    float s0 = c0 ? p[5] : p[4], s1 = c0 ? p[7] : p[6];
    float va = c1 ? t1 : t0;   // -> head q2
    float vb = c1 ? s1 : s0;   // -> head 4+q2
    va += swzf<0x101F>(va); vb += swzf<0x101F>(vb);    // xor4  (ds_swizzle)
    va += dppmov<0x128>(va); vb += dppmov<0x128>(vb);  // xor8  (row_ror:8)
    va += swzf<0x401F>(va); vb += swzf<0x401F>(vb);    // xor16 (ds_swizzle)
    va += __shfl_xor(va, 32, 64); vb += __shfl_xor(vb, 32, 64);  // xor32

    const float ea = __expf((va + qba) * SCALE);
    const float eb = __expf((vb + qbb) * SCALE);
    laccA += ea; laccB += eb;

    // spread e to all lanes in XOR slot order (3 DPP movs per value)
    float r[8];
    r[0] = ea; r[1] = dppmov<0xB1>(ea);
    r[2] = dppmov<0x4E>(ea); r[3] = dppmov<0x4E>(r[1]);
    r[4] = eb; r[5] = dppmov<0xB1>(eb);
    r[6] = dppmov<0x4E>(eb); r[7] = dppmov<0x4E>(r[5]);
#pragma unroll
    for (int j = 0; j < 8; ++j) {
      sc[j].x += r[j] * xv.x; sc[j].y += r[j] * xv.y;
      sc[j].z += r[j] * xv.z; sc[j].w += r[j] * xv.w;
    }
    xv = xn;
  }

  if constexpr (PARTIAL) {
    // cross-wave combine via LDS halving, then wave 0 stores the chunk partial
    // (plain coalesced float4 stores; slot order kept, resolved in k2b).
    __shared__ float4 red[2][8][64];  // 16 KB
    if (wave >= 2) {
#pragma unroll
      for (int j = 0; j < 8; ++j) red[wave - 2][j][lane] = sc[j];
    }
    __syncthreads();
    if (wave < 2) {
#pragma unroll
      for (int j = 0; j < 8; ++j) {
        float4 v = red[wave][j][lane];
        sc[j].x += v.x; sc[j].y += v.y; sc[j].z += v.z; sc[j].w += v.w;
      }
    }
    __syncthreads();
    if (wave == 1) {
#pragma unroll
      for (int j = 0; j < 8; ++j) red[0][j][lane] = sc[j];
    }
    __syncthreads();
    if (wave == 0) {
      float4* pp = (float4*)dst_g + ((size_t)(b * CHUNKS + chunk) * 8) * 64 + lane;
#pragma unroll
      for (int j = 0; j < 8; ++j) {
        float4 v = red[0][j][lane];
        sc[j].x += v.x; sc[j].y += v.y; sc[j].z += v.z; sc[j].w += v.w;
        pp[j * 64] = sc[j];
      }
    }
  } else {
    // fallback: atomic accumulate (used only if ws too small)
    float* sb = dst_g + b * NHEAD * DIMC;
    const int dbase = lane * 4;
#pragma unroll
    for (int j = 0; j < 8; ++j) {
      const int h = (j < 4) ? (q2 ^ j) : (4 + (q2 ^ (j - 4)));
      atomicAdd(&sb[h * DIMC + dbase + 0], sc[j].x);
      atomicAdd(&sb[h * DIMC + dbase + 1], sc[j].y);
      atomicAdd(&sb[h * DIMC + dbase + 2], sc[j].z);
      atomicAdd(&sb[h * DIMC + dbase + 3], sc[j].w);
    }
  }

  if (lane < 4) {
    atomicAdd(&l_g[b * 8 + lane], laccA);
    atomicAdd(&l_g[b * 8 + 4 + lane], laccB);
  }
}

// ---------------- K2b: reduce per-chunk partials -> sctx. Coalesced float4
// reads of the 16.8 MB partial array; tiny scattered stores resolve slot->head.
__global__ __launch_bounds__(128) void k2b_reduce(
    const float4* __restrict__ part, float* __restrict__ sctx_g) {
  const int gid = blockIdx.x * 128 + threadIdx.x;  // 16384 = 32 b * 8 j * 64 lane
  const int lane = gid & 63;
  const int j = (gid >> 6) & 7;
  const int b = gid >> 9;
  const float4* p = part + ((size_t)b * CHUNKS * 8 + j) * 64 + lane;
  float4 acc = make_float4(0.f, 0.f, 0.f, 0.f);
  for (int c = 0; c < CHUNKS; ++c) {
    float4 v = p[(size_t)c * 8 * 64];
    acc.x += v.x; acc.y += v.y; acc.z += v.z; acc.w += v.w;
  }
  const int q2 = lane & 3;
  const int h = (j < 4) ? (q2 ^ j) : (4 + (q2 ^ (j - 4)));
  float4* dst = (float4*)(sctx_g + (b * NHEAD + h) * DIMC) + lane;
  *dst = acc;
}

// ---------------- K3: o = ctx/l @ Wv[:,hcols] + bv ; out = q + o @ Wo + bo
__global__ __launch_bounds__(256) void k3_final(
    const float* __restrict__ x, const float* __restrict__ Wv,
    const float* __restrict__ bv, const float* __restrict__ Wo,
    const float* __restrict__ bo, const float* __restrict__ sctx_g,
    const float* __restrict__ l_g, float* __restrict__ out) {
  const int b = blockIdx.x, tid = threadIdx.x;
  __shared__ float ctxs[NHEAD * DIMC];
  __shared__ float os[DIMC];
  __shared__ float ls[NHEAD];
#pragma unroll
  for (int r = 0; r < NHEAD; ++r)
    ctxs[r * DIMC + tid] = sctx_g[b * NHEAD * DIMC + r * DIMC + tid];
  if (tid < NHEAD) ls[tid] = l_g[b * NHEAD + tid];
  __syncthreads();
  const int h = tid >> 5;
  float s = 0.f;
#pragma unroll 4
  for (int d = 0; d < DIMC; ++d) s += ctxs[h * DIMC + d] * Wv[d * DIMC + tid];
  const float o = s / ls[h] + bv[tid];
  os[tid] = o;
  __syncthreads();
  float acc = bo[tid] + x[(size_t)b * NTOKENS * DIMC + tid];  // q residual
#pragma unroll 4
  for (int j = 0; j < DIMC; ++j) acc += os[j] * Wo[j * DIMC + tid];
  out[b * DIMC + tid] = acc;
}

extern "C" void kernel_launch(void* const* d_in, const int* in_sizes, int n_in,
                              void* d_out, int out_size, void* d_ws, size_t ws_size,
                              hipStream_t stream) {
  const float* x  = (const float*)d_in[0];
  const float* Wq = (const float*)d_in[1];
  const float* bq = (const float*)d_in[2];
  const float* Wk = (const float*)d_in[3];
  const float* bk = (const float*)d_in[4];
  const float* Wv = (const float*)d_in[5];
  const float* bv = (const float*)d_in[6];
  const float* Wo = (const float*)d_in[7];
  const float* bo = (const float*)d_in[8];
  float* ws = (float*)d_ws;
  float* sctx = ws + WS_SCTX;
  float* lg   = ws + WS_L;
  float* qk   = ws + WS_QK;
  float* qb   = ws + WS_QB;
  float* part = ws + WS_PART;

  k1_prep<<<NBATCH, 256, 0, stream>>>(x, Wq, bq, Wk, bk, qk, qb, sctx, lg);
  if (ws_size >= WS_NEEDED_BYTES) {
    k2_attn<true><<<NBATCH * CHUNKS, 256, 0, stream>>>(x, qk, qb, part, lg);
    k2b_reduce<<<NBATCH * NHEAD * 64 / 128, 128, 0, stream>>>((const float4*)part,
                                                              sctx);
  } else {
    k2_attn<false><<<NBATCH * CHUNKS, 256, 0, stream>>>(x, qk, qb, sctx, lg);
  }
  k3_final<<<NBATCH, 256, 0, stream>>>(x, Wv, bv, Wo, bo, sctx, lg,
                                       (float*)d_out);
}

// Round 4
// 455.923 us; speedup vs baseline: 2.9625x; 1.0877x over previous
//
#include <hip/hip_runtime.h>

// Decode attention with projections algebraically folded:
//   score[b,h,n] = x[b,n,:]·qks[b,h,:] + qbs[b,h]        (SCALE folded into qks/qbs)
//   ctx[b,h,:]   = softmax-weighted sum of x rows         (the only big pass)
//   out = q + (ctx @ Wv[:,h] + bv) @ Wo + bo
// R2: killed hot-path global atomics (memory-side RMW serialization).
// R3: k2 latency-bound (1 outstanding load/wave, serial per-token reduce chain)
//     -> 8-token groups, double-buffered loads, batched butterfly (16 indep
//     values per swizzle stage). k1 Wk access coalesced via LDS tile. k2b
//     folded into k3.
// R4: resubmit of R3 unchanged — R3 bench was an infra failure (container
//     died twice, no pytest/compile output), not a kernel failure.

namespace {
constexpr int DIMC = 256;
constexpr int NHEAD = 8;
constexpr int NTOKENS = 8192;
constexpr int NBATCH = 32;
constexpr int TOK_PER_BLOCK = 128;
constexpr int CHUNKS = NTOKENS / TOK_PER_BLOCK;  // 64
constexpr float SCALE = 0.17677669529663687f;    // 1/sqrt(32)

// workspace layout (float offsets)
constexpr int WS_SCTX = 0;                              // [32][8][256] (fallback)
constexpr int WS_L    = NBATCH * NHEAD * DIMC;          // [32][8] sum of e
constexpr int WS_QK   = WS_L + NBATCH * NHEAD;          // [32][8][256] (pre-scaled)
constexpr int WS_QB   = WS_QK + NBATCH * NHEAD * DIMC;  // [32][8]
constexpr int WS_PART = WS_QB + NBATCH * NHEAD;         // [32][64][8][64] float4
constexpr size_t WS_NEEDED_BYTES =
    (size_t)(WS_PART + NBATCH * CHUNKS * NHEAD * DIMC) * 4;  // ~17.3 MB
}  // namespace

template <int CTRL>
__device__ __forceinline__ float dppmov(float v) {
  return __int_as_float(
      __builtin_amdgcn_update_dpp(0, __float_as_int(v), CTRL, 0xF, 0xF, true));
}
template <int PAT>
__device__ __forceinline__ float swzf(float v) {
  return __int_as_float(__builtin_amdgcn_ds_swizzle(__float_as_int(v), PAT));
}

// ---------------- K1: Q = x[b,0,:]@Wq+bq ; qks[b,h,:] = SCALE*(Wk[:,hcols]@Q)
__global__ __launch_bounds__(256) void k1_prep(
    const float* __restrict__ x, const float* __restrict__ Wq,
    const float* __restrict__ bq, const float* __restrict__ Wk,
    const float* __restrict__ bk, float* __restrict__ qk_g,
    float* __restrict__ qb_g, float* __restrict__ sctx_g,
    float* __restrict__ l_g) {
  const int b = blockIdx.x, tid = threadIdx.x;
  __shared__ float xs[DIMC];
  __shared__ float Qs[DIMC];
  __shared__ float wk[DIMC][33];  // padded: conflict-free row-per-thread reads
  xs[tid] = x[(size_t)b * NTOKENS * DIMC + tid];
  // zero accumulators (ws is poisoned each launch)
#pragma unroll
  for (int r = 0; r < NHEAD; ++r) sctx_g[b * NHEAD * DIMC + r * DIMC + tid] = 0.f;
  if (tid < NHEAD) l_g[b * NHEAD + tid] = 0.f;
  __syncthreads();
  {  // Q = x0 @ Wq + bq  (coalesced in tid; 4-way split accumulators)
    float a0 = bq[tid], a1 = 0.f, a2 = 0.f, a3 = 0.f;
#pragma unroll 8
    for (int d = 0; d < DIMC; d += 4) {
      a0 += xs[d + 0] * Wq[(d + 0) * DIMC + tid];
      a1 += xs[d + 1] * Wq[(d + 1) * DIMC + tid];
      a2 += xs[d + 2] * Wq[(d + 2) * DIMC + tid];
      a3 += xs[d + 3] * Wq[(d + 3) * DIMC + tid];
    }
    Qs[tid] = (a0 + a1) + (a2 + a3);
  }
  __syncthreads();
  for (int h = 0; h < NHEAD; ++h) {
    // stage Wk[:, h*32..h*32+31] coalesced into padded LDS
#pragma unroll
    for (int kk = 0; kk < 32; ++kk) {
      const int i = kk * 256 + tid;
      wk[i >> 5][i & 31] = Wk[(size_t)(i >> 5) * DIMC + h * 32 + (i & 31)];
    }
    __syncthreads();
    float s0 = 0.f, s1 = 0.f, s2 = 0.f, s3 = 0.f;
#pragma unroll
    for (int j = 0; j < 32; j += 4) {
      s0 += Qs[h * 32 + j + 0] * wk[tid][j + 0];
      s1 += Qs[h * 32 + j + 1] * wk[tid][j + 1];
      s2 += Qs[h * 32 + j + 2] * wk[tid][j + 2];
      s3 += Qs[h * 32 + j + 3] * wk[tid][j + 3];
    }
    qk_g[b * NHEAD * DIMC + h * DIMC + tid] = SCALE * ((s0 + s1) + (s2 + s3));
    __syncthreads();
  }
  if (tid < NHEAD) {
    float s = 0.f;
#pragma unroll
    for (int j = 0; j < 32; ++j) s += Qs[tid * 32 + j] * bk[tid * 32 + j];
    qb_g[b * NHEAD + tid] = SCALE * s;
  }
}

// ---------------- K2: streaming pass over x, 8-token groups, double-buffered.
// Lane i owns d = 4i..4i+3. Head partials: DPP quad reduce (xor1/2), then
// batched butterfly xor4 (swz) / xor8 (dpp ror8) / xor16 (swz) / xor32 (shfl)
// over 16 independent values. sctx slots use XOR head labeling: slot j<4 ->
// head (lane&3)^j, slot 4+j -> 4+((lane&3)^j); resolved in k3.
template <bool PARTIAL>
__global__ __launch_bounds__(256) void k2_attn(
    const float* __restrict__ x, const float* __restrict__ qk_g,
    const float* __restrict__ qb_g, float* __restrict__ dst_g,
    float* __restrict__ l_g) {
  const int b = blockIdx.x >> 6;
  const int chunk = blockIdx.x & (CHUNKS - 1);
  const int tid = threadIdx.x;
  const int wave = tid >> 6;
  const int lane = tid & 63;
  const int q2 = lane & 3;
  const bool c0 = (lane & 1) != 0, c1 = (lane & 2) != 0;

  const float4* qkp = (const float4*)(qk_g + b * NHEAD * DIMC);
  float4 qk[8];
#pragma unroll
  for (int h = 0; h < 8; ++h) qk[h] = qkp[h * 64 + lane];
  const float qba = qb_g[b * 8 + q2];
  const float qbb = qb_g[b * 8 + 4 + q2];

  float4 sc[8];
#pragma unroll
  for (int j = 0; j < 8; ++j) sc[j] = make_float4(0.f, 0.f, 0.f, 0.f);
  float laccA = 0.f, laccB = 0.f;

  const int n0 = chunk * TOK_PER_BLOCK + wave * 32;
  const float4* xp = (const float4*)(x + (size_t)b * NTOKENS * DIMC);

  float4 xa[8], xb[8];
#pragma unroll
  for (int u = 0; u < 8; ++u) xa[u] = xp[(size_t)(n0 + u) * 64 + lane];

#pragma unroll 1
  for (int g = 0; g < 4; ++g) {
    if (g < 3) {  // prefetch next group (uniform branch)
      const int n1 = n0 + (g + 1) * 8;
#pragma unroll
      for (int u = 0; u < 8; ++u) xb[u] = xp[(size_t)(n1 + u) * 64 + lane];
    }
    // ---- process xa (8 tokens) ----
    float va[8], vb[8];
#pragma unroll
    for (int u = 0; u < 8; ++u) {
      float p[8];
#pragma unroll
      for (int h = 0; h < 8; ++h)
        p[h] = xa[u].x * qk[h].x + xa[u].y * qk[h].y + xa[u].z * qk[h].z +
               xa[u].w * qk[h].w;
#pragma unroll
      for (int h = 0; h < 8; ++h) {
        p[h] += dppmov<0xB1>(p[h]);  // xor1
        p[h] += dppmov<0x4E>(p[h]);  // xor2
      }
      float t0 = c0 ? p[1] : p[0], t1 = c0 ? p[3] : p[2];
      float s0 = c0 ? p[5] : p[4], s1 = c0 ? p[7] : p[6];
      va[u] = c1 ? t1 : t0;  // -> head q2
      vb[u] = c1 ? s1 : s0;  // -> head 4+q2
    }
    // batched butterfly: 16 independent chains per stage
#pragma unroll
    for (int u = 0; u < 8; ++u) { va[u] += swzf<0x101F>(va[u]); vb[u] += swzf<0x101F>(vb[u]); }
#pragma unroll
    for (int u = 0; u < 8; ++u) { va[u] += dppmov<0x128>(va[u]); vb[u] += dppmov<0x128>(vb[u]); }
#pragma unroll
    for (int u = 0; u < 8; ++u) { va[u] += swzf<0x401F>(va[u]); vb[u] += swzf<0x401F>(vb[u]); }
#pragma unroll
    for (int u = 0; u < 8; ++u) { va[u] += __shfl_xor(va[u], 32, 64); vb[u] += __shfl_xor(vb[u], 32, 64); }
    float ea[8], eb[8];
#pragma unroll
    for (int u = 0; u < 8; ++u) {
      ea[u] = __expf(va[u] + qba);
      eb[u] = __expf(vb[u] + qbb);
      laccA += ea[u];
      laccB += eb[u];
    }
#pragma unroll
    for (int u = 0; u < 8; ++u) {
      float r0 = ea[u], r1 = dppmov<0xB1>(ea[u]);
      float r2 = dppmov<0x4E>(ea[u]), r3 = dppmov<0x4E>(r1);
      float r4 = eb[u], r5 = dppmov<0xB1>(eb[u]);
      float r6 = dppmov<0x4E>(eb[u]), r7 = dppmov<0x4E>(r5);
      sc[0].x += r0 * xa[u].x; sc[0].y += r0 * xa[u].y; sc[0].z += r0 * xa[u].z; sc[0].w += r0 * xa[u].w;
      sc[1].x += r1 * xa[u].x; sc[1].y += r1 * xa[u].y; sc[1].z += r1 * xa[u].z; sc[1].w += r1 * xa[u].w;
      sc[2].x += r2 * xa[u].x; sc[2].y += r2 * xa[u].y; sc[2].z += r2 * xa[u].z; sc[2].w += r2 * xa[u].w;
      sc[3].x += r3 * xa[u].x; sc[3].y += r3 * xa[u].y; sc[3].z += r3 * xa[u].z; sc[3].w += r3 * xa[u].w;
      sc[4].x += r4 * xa[u].x; sc[4].y += r4 * xa[u].y; sc[4].z += r4 * xa[u].z; sc[4].w += r4 * xa[u].w;
      sc[5].x += r5 * xa[u].x; sc[5].y += r5 * xa[u].y; sc[5].z += r5 * xa[u].z; sc[5].w += r5 * xa[u].w;
      sc[6].x += r6 * xa[u].x; sc[6].y += r6 * xa[u].y; sc[6].z += r6 * xa[u].z; sc[6].w += r6 * xa[u].w;
      sc[7].x += r7 * xa[u].x; sc[7].y += r7 * xa[u].y; sc[7].z += r7 * xa[u].z; sc[7].w += r7 * xa[u].w;
    }
    if (g < 3) {
#pragma unroll
      for (int u = 0; u < 8; ++u) xa[u] = xb[u];
    }
  }

  if constexpr (PARTIAL) {
    // cross-wave combine via LDS halving; wave 0 stores the chunk partial.
    __shared__ float4 red[2][8][64];  // 16 KB
    if (wave >= 2) {
#pragma unroll
      for (int j = 0; j < 8; ++j) red[wave - 2][j][lane] = sc[j];
    }
    __syncthreads();
    if (wave < 2) {
#pragma unroll
      for (int j = 0; j < 8; ++j) {
        float4 v = red[wave][j][lane];
        sc[j].x += v.x; sc[j].y += v.y; sc[j].z += v.z; sc[j].w += v.w;
      }
    }
    __syncthreads();
    if (wave == 1) {
#pragma unroll
      for (int j = 0; j < 8; ++j) red[0][j][lane] = sc[j];
    }
    __syncthreads();
    if (wave == 0) {
      float4* pp = (float4*)dst_g + ((size_t)(b * CHUNKS + chunk) * 8) * 64 + lane;
#pragma unroll
      for (int j = 0; j < 8; ++j) {
        float4 v = red[0][j][lane];
        sc[j].x += v.x; sc[j].y += v.y; sc[j].z += v.z; sc[j].w += v.w;
        pp[j * 64] = sc[j];
      }
    }
  } else {
    float* sb = dst_g + b * NHEAD * DIMC;
    const int dbase = lane * 4;
#pragma unroll
    for (int j = 0; j < 8; ++j) {
      const int h = (j < 4) ? (q2 ^ j) : (4 + (q2 ^ (j - 4)));
      atomicAdd(&sb[h * DIMC + dbase + 0], sc[j].x);
      atomicAdd(&sb[h * DIMC + dbase + 1], sc[j].y);
      atomicAdd(&sb[h * DIMC + dbase + 2], sc[j].z);
      atomicAdd(&sb[h * DIMC + dbase + 3], sc[j].w);
    }
  }

  if (lane < 4) {
    atomicAdd(&l_g[b * 8 + lane], laccA);
    atomicAdd(&l_g[b * 8 + 4 + lane], laccB);
  }
}

// ---------------- K3: (reduce partials ->) ctx ; o = ctx/l @ Wv + bv ;
//                  out = q + o @ Wo + bo
template <bool FROMPART>
__global__ __launch_bounds__(256) void k3_final(
    const float* __restrict__ x, const float* __restrict__ Wv,
    const float* __restrict__ bv, const float* __restrict__ Wo,
    const float* __restrict__ bo, const float* __restrict__ src,
    const float* __restrict__ l_g, float* __restrict__ out) {
  const int b = blockIdx.x, tid = threadIdx.x;
  __shared__ float ctxs[NHEAD * 260];  // padded rows (260 floats, 16B-multiple)
  __shared__ float os[DIMC];
  __shared__ float ls[NHEAD];
  if (tid < NHEAD) ls[tid] = l_g[b * NHEAD + tid];
  if constexpr (FROMPART) {
    const int lane = tid & 63, j = tid >> 6, q2 = lane & 3;  // j in 0..3
    const float4* p0 =
        (const float4*)src + ((size_t)(b * CHUNKS) * 8 + j) * 64 + lane;
    float4 a0 = make_float4(0.f, 0.f, 0.f, 0.f);
    float4 a1 = make_float4(0.f, 0.f, 0.f, 0.f);
    for (int c = 0; c < CHUNKS; ++c) {
      float4 v0 = p0[(size_t)c * 512];
      float4 v1 = p0[(size_t)c * 512 + 256];
      a0.x += v0.x; a0.y += v0.y; a0.z += v0.z; a0.w += v0.w;
      a1.x += v1.x; a1.y += v1.y; a1.z += v1.z; a1.w += v1.w;
    }
    const int h0 = q2 ^ j, h1 = 4 + (q2 ^ j);
    *(float4*)&ctxs[h0 * 260 + lane * 4] = a0;
    *(float4*)&ctxs[h1 * 260 + lane * 4] = a1;
  } else {
#pragma unroll
    for (int r = 0; r < NHEAD; ++r)
      ctxs[r * 260 + tid] = src[b * NHEAD * DIMC + r * DIMC + tid];
  }
  __syncthreads();
  const int h = tid >> 5;
  {
    float s0 = 0.f, s1 = 0.f, s2 = 0.f, s3 = 0.f;
#pragma unroll 8
    for (int d = 0; d < DIMC; d += 4) {
      s0 += ctxs[h * 260 + d + 0] * Wv[(d + 0) * DIMC + tid];
      s1 += ctxs[h * 260 + d + 1] * Wv[(d + 1) * DIMC + tid];
      s2 += ctxs[h * 260 + d + 2] * Wv[(d + 2) * DIMC + tid];
      s3 += ctxs[h * 260 + d + 3] * Wv[(d + 3) * DIMC + tid];
    }
    os[tid] = ((s0 + s1) + (s2 + s3)) / ls[h] + bv[tid];
  }
  __syncthreads();
  {
    float a0 = bo[tid] + x[(size_t)b * NTOKENS * DIMC + tid];  // q residual
    float a1 = 0.f, a2 = 0.f, a3 = 0.f;
#pragma unroll 8
    for (int j = 0; j < DIMC; j += 4) {
      a0 += os[j + 0] * Wo[(j + 0) * DIMC + tid];
      a1 += os[j + 1] * Wo[(j + 1) * DIMC + tid];
      a2 += os[j + 2] * Wo[(j + 2) * DIMC + tid];
      a3 += os[j + 3] * Wo[(j + 3) * DIMC + tid];
    }
    out[b * DIMC + tid] = (a0 + a1) + (a2 + a3);
  }
}

extern "C" void kernel_launch(void* const* d_in, const int* in_sizes, int n_in,
                              void* d_out, int out_size, void* d_ws, size_t ws_size,
                              hipStream_t stream) {
  const float* x  = (const float*)d_in[0];
  const float* Wq = (const float*)d_in[1];
  const float* bq = (const float*)d_in[2];
  const float* Wk = (const float*)d_in[3];
  const float* bk = (const float*)d_in[4];
  const float* Wv = (const float*)d_in[5];
  const float* bv = (const float*)d_in[6];
  const float* Wo = (const float*)d_in[7];
  const float* bo = (const float*)d_in[8];
  float* ws = (float*)d_ws;
  float* sctx = ws + WS_SCTX;
  float* lg   = ws + WS_L;
  float* qk   = ws + WS_QK;
  float* qb   = ws + WS_QB;
  float* part = ws + WS_PART;

  k1_prep<<<NBATCH, 256, 0, stream>>>(x, Wq, bq, Wk, bk, qk, qb, sctx, lg);
  if (ws_size >= WS_NEEDED_BYTES) {
    k2_attn<true><<<NBATCH * CHUNKS, 256, 0, stream>>>(x, qk, qb, part, lg);
    k3_final<true><<<NBATCH, 256, 0, stream>>>(x, Wv, bv, Wo, bo, part, lg,
                                               (float*)d_out);
  } else {
    k2_attn<false><<<NBATCH * CHUNKS, 256, 0, stream>>>(x, qk, qb, sctx, lg);
    k3_final<false><<<NBATCH, 256, 0, stream>>>(x, Wv, bv, Wo, bo, sctx, lg,
                                                (float*)d_out);
  }
}

// Round 5
// 419.392 us; speedup vs baseline: 3.2205x; 1.0871x over previous
//
#include <hip/hip_runtime.h>

// Decode attention with projections algebraically folded:
//   score[b,h,n] = x[b,n,:]·qks[b,h,:] + qbs[b,h]   (SCALE folded into qks/qbs)
//   ctx[b,h,:]   = softmax-weighted sum of x rows    (the only big pass)
//   out = q + (ctx @ Wv[:,h] + bv) @ Wo + bo
// R2: killed hot-path global atomics (memory-side RMW serialization).
// R3/R4: 8-token double-buffered groups. Result: k2 stuck at ~155us in BOTH
//   schedules -> shared invariant = 6 LDS-pipe permutes/token (ds_swizzle +
//   ds_bpermute ~60cyc each; 262K tok x 6 / 256 CU ~= 160us). LDS-permute
//   pipe serialized, VALU 28%, HBM 12%.
// R5: ZERO lgkm ops in hot loop. Reduction all-VALU: DPP reduce-scatter
//   (xor1/2), row_ror:4/8 (quad-class-preserving rotation sums), and gfx950
//   v_permlane16/32_swap for the row/half stages (direction-robust r0+r1
//   form, __has_builtin-guarded). 4-token groups, grid 1024 (full-resident).

namespace {
constexpr int DIMC = 256;
constexpr int NHEAD = 8;
constexpr int NTOKENS = 8192;
constexpr int NBATCH = 32;
constexpr int TOK_PER_BLOCK = 256;                // 4 waves x 64 tokens
constexpr int CHUNKS = NTOKENS / TOK_PER_BLOCK;   // 32
constexpr float SCALE = 0.17677669529663687f;     // 1/sqrt(32)

// workspace layout (float offsets)
constexpr int WS_SCTX = 0;                              // [32][8][256] (fallback)
constexpr int WS_L    = NBATCH * NHEAD * DIMC;          // [32][8] sum of e
constexpr int WS_QK   = WS_L + NBATCH * NHEAD;          // [32][8][256] (pre-scaled)
constexpr int WS_QB   = WS_QK + NBATCH * NHEAD * DIMC;  // [32][8]
constexpr int WS_PART = WS_QB + NBATCH * NHEAD;         // [32][32][8][64] float4
constexpr size_t WS_NEEDED_BYTES =
    (size_t)(WS_PART + NBATCH * CHUNKS * NHEAD * DIMC) * 4;  // ~8.7 MB
}  // namespace

template <int CTRL>
__device__ __forceinline__ float dppmov(float v) {
  return __int_as_float(
      __builtin_amdgcn_update_dpp(0, __float_as_int(v), CTRL, 0xF, 0xF, true));
}
template <int PAT>
__device__ __forceinline__ float swzf(float v) {
  return __int_as_float(__builtin_amdgcn_ds_swizzle(__float_as_int(v), PAT));
}

// Sum across row-pairs (lanes l and l^16). permlane16_swap exchanges rows
// between its two operands; with both = v, r[0]+r[1] = row-pair sum on every
// lane regardless of swap direction. Fallback: ds_swizzle xor16.
__device__ __forceinline__ float sum_x16(float v) {
#if __has_builtin(__builtin_amdgcn_permlane16_swap)
  auto r = __builtin_amdgcn_permlane16_swap(__float_as_int(v), __float_as_int(v),
                                            false, false);
  return __int_as_float(r[0]) + __int_as_float(r[1]);
#else
  return v + swzf<0x401F>(v);
#endif
}
// Sum across wave halves (lanes l and l^32), same trick.
__device__ __forceinline__ float sum_x32(float v) {
#if __has_builtin(__builtin_amdgcn_permlane32_swap)
  auto r = __builtin_amdgcn_permlane32_swap(__float_as_int(v), __float_as_int(v),
                                            false, false);
  return __int_as_float(r[0]) + __int_as_float(r[1]);
#else
  return v + __shfl_xor(v, 32, 64);
#endif
}

// ---------------- K1: Q = x[b,0,:]@Wq+bq ; qks[b,h,:] = SCALE*(Wk[:,hcols]@Q)
__global__ __launch_bounds__(256) void k1_prep(
    const float* __restrict__ x, const float* __restrict__ Wq,
    const float* __restrict__ bq, const float* __restrict__ Wk,
    const float* __restrict__ bk, float* __restrict__ qk_g,
    float* __restrict__ qb_g, float* __restrict__ sctx_g,
    float* __restrict__ l_g) {
  const int b = blockIdx.x, tid = threadIdx.x;
  __shared__ float xs[DIMC];
  __shared__ float Qs[DIMC];
  __shared__ float wk[DIMC][33];  // padded: conflict-free row-per-thread reads
  xs[tid] = x[(size_t)b * NTOKENS * DIMC + tid];
  // zero accumulators (ws is poisoned each launch)
#pragma unroll
  for (int r = 0; r < NHEAD; ++r) sctx_g[b * NHEAD * DIMC + r * DIMC + tid] = 0.f;
  if (tid < NHEAD) l_g[b * NHEAD + tid] = 0.f;
  __syncthreads();
  {  // Q = x0 @ Wq + bq  (coalesced in tid; 4-way split accumulators)
    float a0 = bq[tid], a1 = 0.f, a2 = 0.f, a3 = 0.f;
#pragma unroll 8
    for (int d = 0; d < DIMC; d += 4) {
      a0 += xs[d + 0] * Wq[(d + 0) * DIMC + tid];
      a1 += xs[d + 1] * Wq[(d + 1) * DIMC + tid];
      a2 += xs[d + 2] * Wq[(d + 2) * DIMC + tid];
      a3 += xs[d + 3] * Wq[(d + 3) * DIMC + tid];
    }
    Qs[tid] = (a0 + a1) + (a2 + a3);
  }
  __syncthreads();
  for (int h = 0; h < NHEAD; ++h) {
    // stage Wk[:, h*32..h*32+31] coalesced into padded LDS
#pragma unroll
    for (int kk = 0; kk < 32; ++kk) {
      const int i = kk * 256 + tid;
      wk[i >> 5][i & 31] = Wk[(size_t)(i >> 5) * DIMC + h * 32 + (i & 31)];
    }
    __syncthreads();
    float s0 = 0.f, s1 = 0.f, s2 = 0.f, s3 = 0.f;
#pragma unroll
    for (int j = 0; j < 32; j += 4) {
      s0 += Qs[h * 32 + j + 0] * wk[tid][j + 0];
      s1 += Qs[h * 32 + j + 1] * wk[tid][j + 1];
      s2 += Qs[h * 32 + j + 2] * wk[tid][j + 2];
      s3 += Qs[h * 32 + j + 3] * wk[tid][j + 3];
    }
    qk_g[b * NHEAD * DIMC + h * DIMC + tid] = SCALE * ((s0 + s1) + (s2 + s3));
    __syncthreads();
  }
  if (tid < NHEAD) {
    float s = 0.f;
#pragma unroll
    for (int j = 0; j < 32; ++j) s += Qs[tid * 32 + j] * bk[tid * 32 + j];
    qb_g[b * NHEAD + tid] = SCALE * s;
  }
}

// ---------------- K2: streaming pass over x, 4-token double-buffered groups.
// Lane l owns d = 4l..4l+3. Score reduction is ALL-VALU:
//   xor1/xor2: DPP reduce-scatter -> va (head l&3), vb (head 4+(l&3)), quad sums
//   +4/+8:     row_ror:4/8 rotations (orbit {0,4,8,12}, preserves l&3 class)
//   x16/x32:   permlane16/32_swap (VALU) or swizzle/shfl fallback
// sctx slots use XOR head labeling: slot j<4 -> head (l&3)^j, slot 4+j ->
// 4+((l&3)^j); resolved in k3.
template <bool PARTIAL>
__global__ __launch_bounds__(256) void k2_attn(
    const float* __restrict__ x, const float* __restrict__ qk_g,
    const float* __restrict__ qb_g, float* __restrict__ dst_g,
    float* __restrict__ l_g) {
  const int b = blockIdx.x >> 5;
  const int chunk = blockIdx.x & (CHUNKS - 1);
  const int tid = threadIdx.x;
  const int wave = tid >> 6;
  const int lane = tid & 63;
  const int q2 = lane & 3;
  const bool c0 = (lane & 1) != 0, c1 = (lane & 2) != 0;

  const float4* qkp = (const float4*)(qk_g + b * NHEAD * DIMC);
  float4 qk[8];
#pragma unroll
  for (int h = 0; h < 8; ++h) qk[h] = qkp[h * 64 + lane];
  const float qba = qb_g[b * 8 + q2];
  const float qbb = qb_g[b * 8 + 4 + q2];

  float4 sc[8];
#pragma unroll
  for (int j = 0; j < 8; ++j) sc[j] = make_float4(0.f, 0.f, 0.f, 0.f);
  float laccA = 0.f, laccB = 0.f;

  const int n0 = chunk * TOK_PER_BLOCK + wave * 64;
  const float4* xp = (const float4*)(x + (size_t)b * NTOKENS * DIMC);

  float4 xa[4], xb[4];
#pragma unroll
  for (int u = 0; u < 4; ++u) xa[u] = xp[(size_t)(n0 + u) * 64 + lane];

#pragma unroll 1
  for (int g = 0; g < 16; ++g) {
    if (g < 15) {  // prefetch next group (uniform branch)
      const int n1 = n0 + (g + 1) * 4;
#pragma unroll
      for (int u = 0; u < 4; ++u) xb[u] = xp[(size_t)(n1 + u) * 64 + lane];
    }
#pragma unroll
    for (int u = 0; u < 4; ++u) {
      float p[8];
#pragma unroll
      for (int h = 0; h < 8; ++h)
        p[h] = xa[u].x * qk[h].x + xa[u].y * qk[h].y + xa[u].z * qk[h].z +
               xa[u].w * qk[h].w;
      // DPP reduce-scatter: xor1 (pairs), xor2 (quads)
      float q01 = (c0 ? p[1] : p[0]) + dppmov<0xB1>(c0 ? p[0] : p[1]);
      float q23 = (c0 ? p[3] : p[2]) + dppmov<0xB1>(c0 ? p[2] : p[3]);
      float q45 = (c0 ? p[5] : p[4]) + dppmov<0xB1>(c0 ? p[4] : p[5]);
      float q67 = (c0 ? p[7] : p[6]) + dppmov<0xB1>(c0 ? p[6] : p[7]);
      float va = (c1 ? q23 : q01) + dppmov<0x4E>(c1 ? q01 : q23);  // head q2
      float vb = (c1 ? q67 : q45) + dppmov<0x4E>(c1 ? q45 : q67);  // head 4+q2
      // sum the 4 quads within each 16-lane row: rotations preserve l&3
      va += dppmov<0x124>(va); vb += dppmov<0x124>(vb);  // row_ror:4
      va += dppmov<0x128>(va); vb += dppmov<0x128>(vb);  // row_ror:8
      // cross-row and cross-half (VALU permlane swaps)
      va = sum_x16(va); vb = sum_x16(vb);
      va = sum_x32(va); vb = sum_x32(vb);

      const float ea = __expf(va + qba);
      const float eb = __expf(vb + qbb);
      laccA += ea; laccB += eb;

      // spread e within quad to XOR slot order (pure quad DPP)
      float r0 = ea, r1 = dppmov<0xB1>(ea);
      float r2 = dppmov<0x4E>(ea), r3 = dppmov<0x4E>(r1);
      float r4 = eb, r5 = dppmov<0xB1>(eb);
      float r6 = dppmov<0x4E>(eb), r7 = dppmov<0x4E>(r5);
      sc[0].x += r0 * xa[u].x; sc[0].y += r0 * xa[u].y; sc[0].z += r0 * xa[u].z; sc[0].w += r0 * xa[u].w;
      sc[1].x += r1 * xa[u].x; sc[1].y += r1 * xa[u].y; sc[1].z += r1 * xa[u].z; sc[1].w += r1 * xa[u].w;
      sc[2].x += r2 * xa[u].x; sc[2].y += r2 * xa[u].y; sc[2].z += r2 * xa[u].z; sc[2].w += r2 * xa[u].w;
      sc[3].x += r3 * xa[u].x; sc[3].y += r3 * xa[u].y; sc[3].z += r3 * xa[u].z; sc[3].w += r3 * xa[u].w;
      sc[4].x += r4 * xa[u].x; sc[4].y += r4 * xa[u].y; sc[4].z += r4 * xa[u].z; sc[4].w += r4 * xa[u].w;
      sc[5].x += r5 * xa[u].x; sc[5].y += r5 * xa[u].y; sc[5].z += r5 * xa[u].z; sc[5].w += r5 * xa[u].w;
      sc[6].x += r6 * xa[u].x; sc[6].y += r6 * xa[u].y; sc[6].z += r6 * xa[u].z; sc[6].w += r6 * xa[u].w;
      sc[7].x += r7 * xa[u].x; sc[7].y += r7 * xa[u].y; sc[7].z += r7 * xa[u].z; sc[7].w += r7 * xa[u].w;
    }
    if (g < 15) {
#pragma unroll
      for (int u = 0; u < 4; ++u) xa[u] = xb[u];
    }
  }

  if constexpr (PARTIAL) {
    // cross-wave combine via LDS halving; wave 0 stores the chunk partial.
    __shared__ float4 red[2][8][64];  // 16 KB
    if (wave >= 2) {
#pragma unroll
      for (int j = 0; j < 8; ++j) red[wave - 2][j][lane] = sc[j];
    }
    __syncthreads();
    if (wave < 2) {
#pragma unroll
      for (int j = 0; j < 8; ++j) {
        float4 v = red[wave][j][lane];
        sc[j].x += v.x; sc[j].y += v.y; sc[j].z += v.z; sc[j].w += v.w;
      }
    }
    __syncthreads();
    if (wave == 1) {
#pragma unroll
      for (int j = 0; j < 8; ++j) red[0][j][lane] = sc[j];
    }
    __syncthreads();
    if (wave == 0) {
      float4* pp = (float4*)dst_g + ((size_t)(b * CHUNKS + chunk) * 8) * 64 + lane;
#pragma unroll
      for (int j = 0; j < 8; ++j) {
        float4 v = red[0][j][lane];
        sc[j].x += v.x; sc[j].y += v.y; sc[j].z += v.z; sc[j].w += v.w;
        pp[j * 64] = sc[j];
      }
    }
  } else {
    float* sb = dst_g + b * NHEAD * DIMC;
    const int dbase = lane * 4;
#pragma unroll
    for (int j = 0; j < 8; ++j) {
      const int h = (j < 4) ? (q2 ^ j) : (4 + (q2 ^ (j - 4)));
      atomicAdd(&sb[h * DIMC + dbase + 0], sc[j].x);
      atomicAdd(&sb[h * DIMC + dbase + 1], sc[j].y);
      atomicAdd(&sb[h * DIMC + dbase + 2], sc[j].z);
      atomicAdd(&sb[h * DIMC + dbase + 3], sc[j].w);
    }
  }

  if (lane < 4) {
    atomicAdd(&l_g[b * 8 + lane], laccA);
    atomicAdd(&l_g[b * 8 + 4 + lane], laccB);
  }
}

// ---------------- K3: (reduce partials ->) ctx ; o = ctx/l @ Wv + bv ;
//                  out = q + o @ Wo + bo
template <bool FROMPART>
__global__ __launch_bounds__(256) void k3_final(
    const float* __restrict__ x, const float* __restrict__ Wv,
    const float* __restrict__ bv, const float* __restrict__ Wo,
    const float* __restrict__ bo, const float* __restrict__ src,
    const float* __restrict__ l_g, float* __restrict__ out) {
  const int b = blockIdx.x, tid = threadIdx.x;
  __shared__ float ctxs[NHEAD * 260];  // padded rows
  __shared__ float os[DIMC];
  __shared__ float ls[NHEAD];
  if (tid < NHEAD) ls[tid] = l_g[b * NHEAD + tid];
  if constexpr (FROMPART) {
    const int lane = tid & 63, j = tid >> 6, q2 = lane & 3;  // j in 0..3
    const float4* p0 =
        (const float4*)src + ((size_t)(b * CHUNKS) * 8 + j) * 64 + lane;
    float4 a0 = make_float4(0.f, 0.f, 0.f, 0.f);
    float4 a1 = make_float4(0.f, 0.f, 0.f, 0.f);
    for (int c = 0; c < CHUNKS; ++c) {
      float4 v0 = p0[(size_t)c * 512];
      float4 v1 = p0[(size_t)c * 512 + 256];
      a0.x += v0.x; a0.y += v0.y; a0.z += v0.z; a0.w += v0.w;
      a1.x += v1.x; a1.y += v1.y; a1.z += v1.z; a1.w += v1.w;
    }
    const int h0 = q2 ^ j, h1 = 4 + (q2 ^ j);
    *(float4*)&ctxs[h0 * 260 + lane * 4] = a0;
    *(float4*)&ctxs[h1 * 260 + lane * 4] = a1;
  } else {
#pragma unroll
    for (int r = 0; r < NHEAD; ++r)
      ctxs[r * 260 + tid] = src[b * NHEAD * DIMC + r * DIMC + tid];
  }
  __syncthreads();
  const int h = tid >> 5;
  {
    float s0 = 0.f, s1 = 0.f, s2 = 0.f, s3 = 0.f;
#pragma unroll 8
    for (int d = 0; d < DIMC; d += 4) {
      s0 += ctxs[h * 260 + d + 0] * Wv[(d + 0) * DIMC + tid];
      s1 += ctxs[h * 260 + d + 1] * Wv[(d + 1) * DIMC + tid];
      s2 += ctxs[h * 260 + d + 2] * Wv[(d + 2) * DIMC + tid];
      s3 += ctxs[h * 260 + d + 3] * Wv[(d + 3) * DIMC + tid];
    }
    os[tid] = ((s0 + s1) + (s2 + s3)) / ls[h] + bv[tid];
  }
  __syncthreads();
  {
    float a0 = bo[tid] + x[(size_t)b * NTOKENS * DIMC + tid];  // q residual
    float a1 = 0.f, a2 = 0.f, a3 = 0.f;
#pragma unroll 8
    for (int j = 0; j < DIMC; j += 4) {
      a0 += os[j + 0] * Wo[(j + 0) * DIMC + tid];
      a1 += os[j + 1] * Wo[(j + 1) * DIMC + tid];
      a2 += os[j + 2] * Wo[(j + 2) * DIMC + tid];
      a3 += os[j + 3] * Wo[(j + 3) * DIMC + tid];
    }
    out[b * DIMC + tid] = (a0 + a1) + (a2 + a3);
  }
}

extern "C" void kernel_launch(void* const* d_in, const int* in_sizes, int n_in,
                              void* d_out, int out_size, void* d_ws, size_t ws_size,
                              hipStream_t stream) {
  const float* x  = (const float*)d_in[0];
  const float* Wq = (const float*)d_in[1];
  const float* bq = (const float*)d_in[2];
  const float* Wk = (const float*)d_in[3];
  const float* bk = (const float*)d_in[4];
  const float* Wv = (const float*)d_in[5];
  const float* bv = (const float*)d_in[6];
  const float* Wo = (const float*)d_in[7];
  const float* bo = (const float*)d_in[8];
  float* ws = (float*)d_ws;
  float* sctx = ws + WS_SCTX;
  float* lg   = ws + WS_L;
  float* qk   = ws + WS_QK;
  float* qb   = ws + WS_QB;
  float* part = ws + WS_PART;

  k1_prep<<<NBATCH, 256, 0, stream>>>(x, Wq, bq, Wk, bk, qk, qb, sctx, lg);
  if (ws_size >= WS_NEEDED_BYTES) {
    k2_attn<true><<<NBATCH * CHUNKS, 256, 0, stream>>>(x, qk, qb, part, lg);
    k3_final<true><<<NBATCH, 256, 0, stream>>>(x, Wv, bv, Wo, bo, part, lg,
                                               (float*)d_out);
  } else {
    k2_attn<false><<<NBATCH * CHUNKS, 256, 0, stream>>>(x, qk, qb, sctx, lg);
    k3_final<false><<<NBATCH, 256, 0, stream>>>(x, Wv, bv, Wo, bo, sctx, lg,
                                                (float*)d_out);
  }
}